// Round 1
// baseline (472.955 us; speedup 1.0000x reference)
//
#include <hip/hip_runtime.h>
#include <hip/hip_bf16.h>
#include <cstdint>
#include <cstddef>

typedef __attribute__((ext_vector_type(8))) short  s8v;
typedef __attribute__((ext_vector_type(4))) short  s4v;
typedef __attribute__((ext_vector_type(8))) __bf16 b8v;
typedef __attribute__((ext_vector_type(4))) float  f32x4;

__device__ __forceinline__ short f2bf(float f){
  unsigned u = __builtin_bit_cast(unsigned, f);
  unsigned r = (u + 0x7fffu + ((u >> 16) & 1u)) >> 16;   // RNE
  return (short)(unsigned short)r;
}

__device__ __forceinline__ f32x4 mfma16(s8v a, s8v b, f32x4 c){
  return __builtin_amdgcn_mfma_f32_16x16x32_bf16(
      __builtin_bit_cast(b8v, a), __builtin_bit_cast(b8v, b), c, 0, 0, 0);
}

// ---------------- LayerNorm over E=1024 -> bf16 ----------------
__global__ __launch_bounds__(256)
void ln_k(const float* __restrict__ x, const float* __restrict__ g,
          const float* __restrict__ b, short* __restrict__ out)
{
  const int row = blockIdx.x, tid = threadIdx.x;
  const float4 v = ((const float4*)(x + (size_t)row*1024))[tid];
  float s  = v.x+v.y+v.z+v.w;
  float s2 = v.x*v.x+v.y*v.y+v.z*v.z+v.w*v.w;
  #pragma unroll
  for (int off=32; off; off>>=1){ s += __shfl_down(s, off); s2 += __shfl_down(s2, off); }
  __shared__ float red[8];
  const int wave = tid>>6, lane = tid&63;
  if (lane==0){ red[wave]=s; red[4+wave]=s2; }
  __syncthreads();
  s  = red[0]+red[1]+red[2]+red[3];
  s2 = red[4]+red[5]+red[6]+red[7];
  const float mean = s*(1.f/1024.f);
  const float rstd = rsqrtf(s2*(1.f/1024.f) - mean*mean + 1e-5f);
  const float4 gv = ((const float4*)g)[tid];
  const float4 bv = ((const float4*)b)[tid];
  s4v o;
  o[0] = f2bf((v.x-mean)*rstd*gv.x + bv.x);
  o[1] = f2bf((v.y-mean)*rstd*gv.y + bv.y);
  o[2] = f2bf((v.z-mean)*rstd*gv.z + bv.z);
  o[3] = f2bf((v.w-mean)*rstd*gv.w + bv.w);
  *(s4v*)(out + (size_t)row*1024 + tid*4) = o;
}

// ---------------- f32 -> bf16 cast (4 elems/thread) ----------------
__global__ __launch_bounds__(256)
void cast_k(const float* __restrict__ in, short* __restrict__ out)
{
  const int i = blockIdx.x*256 + threadIdx.x;
  const float4 v = ((const float4*)in)[i];
  s4v o; o[0]=f2bf(v.x); o[1]=f2bf(v.y); o[2]=f2bf(v.z); o[3]=f2bf(v.w);
  ((s4v*)out)[i] = o;
}

// ------- transpose+cast: in (gridDim.z, E2, D2) f32 -> out (gridDim.z*D2, E2) bf16 -------
// out[(h*D2+d)*E2 + e] = in[h][e][d]   (produces B^T = (N,K) weight layout)
__global__ __launch_bounds__(256)
void tcast_k(const float* __restrict__ in, short* __restrict__ out, int E2, int D2)
{
  __shared__ float t[32][33];
  const int h  = blockIdx.z;
  const int e0 = blockIdx.x*32, d0 = blockIdx.y*32;
  const int tx = threadIdx.x & 31, ty = threadIdx.x >> 5;
  const float* ip = in + (size_t)h*E2*D2;
  #pragma unroll
  for (int r = ty; r < 32; r += 8)
    t[r][tx] = ip[(size_t)(e0+r)*D2 + d0 + tx];
  __syncthreads();
  short* op = out + (size_t)h*D2*E2;
  #pragma unroll
  for (int r = ty; r < 32; r += 8)
    op[(size_t)(d0+r)*E2 + e0 + tx] = f2bf(t[tx][r]);
}

// ---------------- bf16 MFMA GEMM: C = A(M,K) * Bt(N,K)^T  (m97 structure) ----------------
// 128x128 tile, BK=32, 4 waves (2x2, 64x64 each), double-buffered LDS via global_load_lds.
template<int BIAS, int RELU, int RESID, int WF32>
__global__ __launch_bounds__(256, 2)
void gemm_bt(const short* __restrict__ A, const short* __restrict__ Bt,
             const float* __restrict__ bias, const float* __restrict__ resid,
             short* __restrict__ Cb, float* __restrict__ Cf,
             int M, int N, int K)
{
  __shared__ short lds[2][2][128*32];
  const int m0 = blockIdx.y*128, n0 = blockIdx.x*128;
  const int tid  = threadIdx.x;
  const int wave = tid>>6, lane = tid&63;
  const int lo = lane&15, hi = lane>>4;
  const int wm = wave>>1, wn = wave&1;

  f32x4 acc[4][4] = {};
  const int NK = K >> 5;

  auto stage = [&](int buf, int kt){
    const short* Ag = A  + (size_t)m0*K + kt*32;
    const short* Bg = Bt + (size_t)n0*K + kt*32;
    #pragma unroll
    for (int c=0;c<2;c++){
      const int q = (wave*2+c)*64 + lane;      // 16B-chunk index in [0,512)
      const int r = q>>2, cc = q&3;            // row 0..127, col-chunk (8 bf16)
      __builtin_amdgcn_global_load_lds(
        (const __attribute__((address_space(1))) void*)(Ag + (size_t)r*K + cc*8),
        (__attribute__((address_space(3))) void*)(&lds[buf][0][(wave*2+c)*512]),
        16, 0, 0);
      __builtin_amdgcn_global_load_lds(
        (const __attribute__((address_space(1))) void*)(Bg + (size_t)r*K + cc*8),
        (__attribute__((address_space(3))) void*)(&lds[buf][1][(wave*2+c)*512]),
        16, 0, 0);
    }
  };

  stage(0, 0);
  int cur = 0;
  for (int kt=0; kt<NK; kt++){
    __syncthreads();                     // drains vmcnt -> staged tile visible
    if (kt+1 < NK) stage(cur^1, kt+1);   // prefetch overlaps compute below
    const short* la = &lds[cur][0][0];
    const short* lb = &lds[cur][1][0];
    s8v af[4], bfr[4];
    #pragma unroll
    for (int i=0;i<4;i++)
      af[i] = *(const s8v*)(la + (wm*64 + i*16 + lo)*32 + hi*8);
    #pragma unroll
    for (int j=0;j<4;j++)
      bfr[j] = *(const s8v*)(lb + (wn*64 + j*16 + lo)*32 + hi*8);
    #pragma unroll
    for (int i=0;i<4;i++)
      #pragma unroll
      for (int j=0;j<4;j++)
        acc[i][j] = mfma16(af[i], bfr[j], acc[i][j]);
    cur ^= 1;
  }

  #pragma unroll
  for (int i=0;i<4;i++){
    const int row = m0 + wm*64 + i*16 + hi*4;
    #pragma unroll
    for (int j=0;j<4;j++){
      const int col = n0 + wn*64 + j*16 + lo;
      const float bv = BIAS ? bias[col] : 0.0f;
      #pragma unroll
      for (int r=0;r<4;r++){
        float v = acc[i][j][r] + bv;
        if (RELU) v = fmaxf(v, 0.0f);
        const size_t idx = (size_t)(row + r)*N + col;
        if (RESID) v += resid[idx];
        if (WF32) Cf[idx] = v; else Cb[idx] = f2bf(v);
      }
    }
  }
}

// ---------------- flash attention (bf16 in/out, f32 softmax state) ----------------
// grid (B*H, T/64); 4 waves x 16 Q rows; KV blocks of 32; per-wave only (no barriers).
template<int CAUSAL>
__global__ __launch_bounds__(256)
void attn_k(const short* __restrict__ Q, int ldq,
            const short* __restrict__ K, int ldk,
            const short* __restrict__ V, int ldv,
            const int* __restrict__ msk,
            short* __restrict__ O, int ldo,
            int H, int Tq, int Sk)
{
  __shared__ short plds[4][512];             // per-wave 16x32 bf16 P tile
  const int bh = blockIdx.x;
  const int b = bh / H, h = bh % H;
  const int tid = threadIdx.x;
  const int wave = tid>>6, lane = tid&63;
  const int lo = lane&15, hi = lane>>4;
  const int t0 = blockIdx.y*64 + wave*16;

  const short* Qb = Q + (size_t)(b*Tq)*ldq + h*64;
  const short* Kb = K + (size_t)(b*Sk)*ldk + h*64;
  const short* Vb = V + (size_t)(b*Sk)*ldv + h*64;
  const int*   mb = msk + (size_t)b*Sk;

  const s8v qa0 = *(const s8v*)(Qb + (size_t)(t0+lo)*ldq + hi*8);
  const s8v qa1 = *(const s8v*)(Qb + (size_t)(t0+lo)*ldq + 32 + hi*8);

  float mrow[4], lrow[4];
  f32x4 oacc[4] = {};
  #pragma unroll
  for (int r=0;r<4;r++){ mrow[r] = -INFINITY; lrow[r] = 0.f; }

  const int nblk = CAUSAL ? (t0/32 + 1) : (Sk/32);
  short* myp = plds[wave];
  const float sc = 0.03125f;                 // E^-0.5 = 1024^-0.5

  for (int it=0; it<nblk; it++){
    const int s0 = it*32;
    const short* k0p = Kb + (size_t)(s0+lo)*ldk;
    const short* k1p = Kb + (size_t)(s0+16+lo)*ldk;
    const s8v kb00 = *(const s8v*)(k0p + hi*8);
    const s8v kb01 = *(const s8v*)(k0p + 32 + hi*8);
    const s8v kb10 = *(const s8v*)(k1p + hi*8);
    const s8v kb11 = *(const s8v*)(k1p + 32 + hi*8);
    f32x4 sa = {}, sb = {};
    sa = mfma16(qa0, kb00, sa); sa = mfma16(qa1, kb01, sa);
    sb = mfma16(qa0, kb10, sb); sb = mfma16(qa1, kb11, sb);

    const int km0 = mb[s0+lo];
    const int km1 = mb[s0+16+lo];
    float p0[4], p1[4], mx[4];
    #pragma unroll
    for (int r=0;r<4;r++){
      const int trow = t0 + hi*4 + r;
      const bool ok0 = km0 && (!CAUSAL || (s0+lo)    <= trow);
      const bool ok1 = km1 && (!CAUSAL || (s0+16+lo) <= trow);
      p0[r] = ok0 ? sa[r]*sc : -1e9f;
      p1[r] = ok1 ? sb[r]*sc : -1e9f;
      mx[r] = fmaxf(p0[r], p1[r]);
    }
    #pragma unroll
    for (int off=1; off<16; off<<=1){
      #pragma unroll
      for (int r=0;r<4;r++) mx[r] = fmaxf(mx[r], __shfl_xor(mx[r], off, 16));
    }
    float rs[4];
    #pragma unroll
    for (int r=0;r<4;r++){
      const float mn  = fmaxf(mrow[r], mx[r]);
      const float fac = __expf(mrow[r] - mn);
      mrow[r] = mn;
      p0[r] = __expf(p0[r] - mn);
      p1[r] = __expf(p1[r] - mn);
      rs[r] = p0[r] + p1[r];
      lrow[r] *= fac;
      #pragma unroll
      for (int f=0; f<4; f++) oacc[f][r] *= fac;
    }
    #pragma unroll
    for (int off=1; off<16; off<<=1){
      #pragma unroll
      for (int r=0;r<4;r++) rs[r] += __shfl_xor(rs[r], off, 16);
    }
    #pragma unroll
    for (int r=0;r<4;r++) lrow[r] += rs[r];

    // P (16x32) -> LDS in (t,s) layout, then re-read as MFMA A-fragments
    #pragma unroll
    for (int r=0;r<4;r++){
      myp[(hi*4+r)*32 + lo]      = f2bf(p0[r]);
      myp[(hi*4+r)*32 + 16 + lo] = f2bf(p1[r]);
    }
    asm volatile("s_waitcnt lgkmcnt(0)" ::: "memory");
    const s8v pa = *(const s8v*)(myp + lo*32 + hi*8);
    #pragma unroll
    for (int f=0; f<4; f++){
      const short* vp = Vb + (size_t)(s0 + hi*8)*ldv + f*16 + lo;
      s8v vb;
      #pragma unroll
      for (int e=0;e<8;e++) vb[e] = vp[(size_t)e*ldv];
      oacc[f] = mfma16(pa, vb, oacc[f]);
    }
  }

  short* Ob = O + (size_t)(b*Tq)*ldo + h*64;
  #pragma unroll
  for (int f=0; f<4; f++){
    #pragma unroll
    for (int r=0;r<4;r++){
      const float v = oacc[f][r] / lrow[r];
      Ob[(size_t)(t0+hi*4+r)*ldo + f*16 + lo] = f2bf(v);
    }
  }
}

// =============================== host ===============================
extern "C" void kernel_launch(void* const* d_in, const int* in_sizes, int n_in,
                              void* d_out, int out_size, void* d_ws, size_t ws_size,
                              hipStream_t stream)
{
  (void)in_sizes; (void)n_in; (void)out_size; (void)ws_size;
  const float* x    = (const float*)d_in[0];
  const int*   xm   = (const int*)  d_in[1];
  const float* ca   = (const float*)d_in[2];
  const int*   cam  = (const int*)  d_in[3];
  const float* Wq_s = (const float*)d_in[4];
  const float* Wk_s = (const float*)d_in[5];
  const float* Wv_s = (const float*)d_in[6];
  const float* Wo_s = (const float*)d_in[7];
  const float* bo_s = (const float*)d_in[8];
  const float* Wq_c = (const float*)d_in[9];
  const float* Wk_c = (const float*)d_in[10];
  const float* Wv_c = (const float*)d_in[11];
  const float* Wo_c = (const float*)d_in[12];
  const float* bo_c = (const float*)d_in[13];
  const float* ln1g = (const float*)d_in[14];
  const float* ln1b = (const float*)d_in[15];
  const float* ln2g = (const float*)d_in[16];
  const float* ln2b = (const float*)d_in[17];
  const float* ln3g = (const float*)d_in[18];
  const float* ln3b = (const float*)d_in[19];
  const float* W1   = (const float*)d_in[20];
  const float* b1   = (const float*)d_in[21];
  const float* W2   = (const float*)d_in[22];
  const float* b2   = (const float*)d_in[23];
  float* out = (float*)d_out;

  char* ws = (char*)d_ws;
  size_t off = 0;
  auto alloc = [&](size_t bytes)->void*{
    void* p = ws + off; off += (bytes + 255) & ~(size_t)255; return p; };

  short* w_qkv_s = (short*)alloc((size_t)3072*1024*2);
  short* w_o_s   = (short*)alloc((size_t)1024*1024*2);
  short* w_q_c   = (short*)alloc((size_t)1024*1024*2);
  short* w_kv_c  = (short*)alloc((size_t)2048*1024*2);
  short* w_o_c   = (short*)alloc((size_t)1024*1024*2);
  short* w_1     = (short*)alloc((size_t)4096*1024*2);
  short* w_2     = (short*)alloc((size_t)1024*4096*2);
  short* xn      = (short*)alloc((size_t)4096*1024*2);
  short* cab     = (short*)alloc((size_t)4096*1024*2);
  short* qkv     = (short*)alloc((size_t)4096*3072*2);
  short* attno   = (short*)alloc((size_t)4096*1024*2);
  float* xres    = (float*)alloc((size_t)4096*1024*4);
  short* hffn    = (short*)alloc((size_t)4096*4096*2);
  short* kvbuf   = qkv + (size_t)4096*1024;

  // weight repacks -> B^T (N,K) bf16
  tcast_k<<<dim3(32,  2,16),256,0,stream>>>(Wq_s, w_qkv_s,           1024,   64);
  tcast_k<<<dim3(32,  2,16),256,0,stream>>>(Wk_s, w_qkv_s+1024*1024, 1024,   64);
  tcast_k<<<dim3(32,  2,16),256,0,stream>>>(Wv_s, w_qkv_s+2048*1024, 1024,   64);
  tcast_k<<<dim3(32, 32, 1),256,0,stream>>>(Wo_s, w_o_s,             1024, 1024);
  tcast_k<<<dim3(32,  2,16),256,0,stream>>>(Wq_c, w_q_c,             1024,   64);
  tcast_k<<<dim3(32,  2,16),256,0,stream>>>(Wk_c, w_kv_c,            1024,   64);
  tcast_k<<<dim3(32,  2,16),256,0,stream>>>(Wv_c, w_kv_c+1024*1024,  1024,   64);
  tcast_k<<<dim3(32, 32, 1),256,0,stream>>>(Wo_c, w_o_c,             1024, 1024);
  tcast_k<<<dim3(32,128, 1),256,0,stream>>>(W1,   w_1,               1024, 4096);
  tcast_k<<<dim3(128,32, 1),256,0,stream>>>(W2,   w_2,               4096, 1024);
  cast_k<<<4096,256,0,stream>>>(ca, cab);

  // --- self attention ---
  ln_k<<<4096,256,0,stream>>>(x, ln1g, ln1b, xn);
  gemm_bt<0,0,0,0><<<dim3(24,32),256,0,stream>>>(xn, w_qkv_s, nullptr, nullptr,
                                                 qkv, nullptr, 4096, 3072, 1024);
  attn_k<1><<<dim3(64,16),256,0,stream>>>(qkv, 3072, qkv+1024, 3072, qkv+2048, 3072,
                                          xm, attno, 1024, 16, 1024, 1024);
  gemm_bt<1,0,1,1><<<dim3(8,32),256,0,stream>>>(attno, w_o_s, bo_s, x,
                                                nullptr, xres, 4096, 1024, 1024);

  // --- cross attention (K,V from raw ca) ---
  ln_k<<<4096,256,0,stream>>>(xres, ln2g, ln2b, xn);
  gemm_bt<0,0,0,0><<<dim3(8,32),256,0,stream>>>(xn, w_q_c, nullptr, nullptr,
                                                qkv, nullptr, 4096, 1024, 1024);
  gemm_bt<0,0,0,0><<<dim3(16,32),256,0,stream>>>(cab, w_kv_c, nullptr, nullptr,
                                                 kvbuf, nullptr, 4096, 2048, 1024);
  attn_k<0><<<dim3(64,16),256,0,stream>>>(qkv, 1024, kvbuf, 2048, kvbuf+1024, 2048,
                                          cam, attno, 1024, 16, 1024, 1024);
  gemm_bt<1,0,1,1><<<dim3(8,32),256,0,stream>>>(attno, w_o_c, bo_c, xres,
                                                nullptr, xres, 4096, 1024, 1024);

  // --- FFN ---
  ln_k<<<4096,256,0,stream>>>(xres, ln3g, ln3b, xn);
  gemm_bt<1,1,0,0><<<dim3(32,32),256,0,stream>>>(xn, w_1, b1, nullptr,
                                                 hffn, nullptr, 4096, 4096, 1024);
  gemm_bt<1,0,1,1><<<dim3(8,32),256,0,stream>>>(hffn, w_2, b2, xres,
                                                nullptr, out, 4096, 1024, 4096);
}